// Round 5
// baseline (296.661 us; speedup 1.0000x reference)
//
#include <hip/hip_runtime.h>
#include <hip/hip_bf16.h>

// GNN forward: 3 layers of COO SpMM + gating, mean over layer embeddings.
// N=50000, E=800000, D=96.
//
// Round-9: round-8 structure + non-temporal cache hints on ALL streaming
// accesses (ELL, ego_out, bucket buffers, X, edge lists, acc). Only the
// 3.2 MB gather plane (+ self-row reads) stays temporal.
//  Evidence: r8 slicing was a null on gather rate (same 2.4M line-req/layer,
//  same ~4 TB/s) -> capacity alone wasn't it. Hypotheses: (a) per-pass
//  ~13 MB streams evict the plane from the 4 MB per-XCD L2 (pollution);
//  (b) pull reads hit lines dirty in remote XCDs' L2 (slow snoop path).
//  nt-loads keep streams out of L2; nt-stores push producer output toward
//  L3 so next-layer gathers are clean fills. Single-variable change vs r8.

#define N_NODES 50000
#define N_EDGES 800000
#define EMB 96
#define C16 12                    // 16B bf16 chunks per row
#define LAYER_NUM 3
#define PAD 64                    // ELL slots per row
#define NCHUNK (N_NODES * C16)    // 600000 bf16 chunks total
#define NSLICE 3
#define PLANE_U4 (N_NODES * 4)    // uint4 per 64B plane (200000)

#define NBUCK 196                 // ceil(50000/256) coarse buckets (row>>8)
#define RPB 256                   // rows per bucket
#define CAP 5000                  // record capacity per bucket
#define EDGE_BLOCKS 782           // ceil(200000 quad-edges / 256)
#define CONV_BLOCKS 2344          // ceil(600000 chunks / 256)

// ---- non-temporal helpers (clang builtin needs scalar/vector types) ----
typedef unsigned uv4 __attribute__((ext_vector_type(4)));
typedef int      iv4 __attribute__((ext_vector_type(4)));
typedef float    fv4 __attribute__((ext_vector_type(4)));
typedef unsigned uv2 __attribute__((ext_vector_type(2)));
typedef int      iv2 __attribute__((ext_vector_type(2)));

__device__ __forceinline__ uint4 ntl_u4(const uint4* p) {
    uv4 t = __builtin_nontemporal_load((const uv4*)p);
    return make_uint4(t.x, t.y, t.z, t.w);
}
__device__ __forceinline__ int4 ntl_i4(const int4* p) {
    iv4 t = __builtin_nontemporal_load((const iv4*)p);
    return make_int4(t.x, t.y, t.z, t.w);
}
__device__ __forceinline__ float4 ntl_f4(const float4* p) {
    fv4 t = __builtin_nontemporal_load((const fv4*)p);
    return make_float4(t.x, t.y, t.z, t.w);
}
__device__ __forceinline__ int2 ntl_i2(const int2* p) {
    iv2 t = __builtin_nontemporal_load((const iv2*)p);
    return make_int2(t.x, t.y);
}
__device__ __forceinline__ uint2 ntl_u2(const uint2* p) {
    uv2 t = __builtin_nontemporal_load((const uv2*)p);
    return make_uint2(t.x, t.y);
}
__device__ __forceinline__ void nts_u4(uint4* p, uint4 v) {
    uv4 t = {v.x, v.y, v.z, v.w};
    __builtin_nontemporal_store(t, (uv4*)p);
}
__device__ __forceinline__ void nts_u2(uint2* p, uint2 v) {
    uv2 t = {v.x, v.y};
    __builtin_nontemporal_store(t, (uv2*)p);
}
__device__ __forceinline__ void nts_i2(int2* p, int2 v) {
    iv2 t = {v.x, v.y};
    __builtin_nontemporal_store(t, (iv2*)p);
}
__device__ __forceinline__ void nts_f4(float4* p, float4 v) {
    fv4 t = {v.x, v.y, v.z, v.w};
    __builtin_nontemporal_store(t, (fv4*)p);
}

__device__ __forceinline__ float bflo(unsigned u) { return __uint_as_float(u << 16); }
__device__ __forceinline__ float bfhi(unsigned u) { return __uint_as_float(u & 0xffff0000u); }

__device__ __forceinline__ void fma_bf8(float* s, float v, const uint4& u) {
    s[0] = fmaf(v, bflo(u.x), s[0]);
    s[1] = fmaf(v, bfhi(u.x), s[1]);
    s[2] = fmaf(v, bflo(u.y), s[2]);
    s[3] = fmaf(v, bfhi(u.y), s[3]);
    s[4] = fmaf(v, bflo(u.z), s[4]);
    s[5] = fmaf(v, bfhi(u.z), s[5]);
    s[6] = fmaf(v, bflo(u.w), s[6]);
    s[7] = fmaf(v, bfhi(u.w), s[7]);
}

__device__ __forceinline__ void unpack8(float* d, const uint4& u) {
    d[0] = bflo(u.x); d[1] = bfhi(u.x);
    d[2] = bflo(u.y); d[3] = bfhi(u.y);
    d[4] = bflo(u.z); d[5] = bfhi(u.z);
    d[6] = bflo(u.w); d[7] = bfhi(u.w);
}

// RNE pack: a -> low 16, b -> high 16
__device__ __forceinline__ unsigned packbf(float a, float b) {
    unsigned ua = __float_as_uint(a);
    unsigned ub = __float_as_uint(b);
    ua = (ua + 0x7fffu + ((ua >> 16) & 1u)) >> 16;
    ub = (ub + 0x7fffu + ((ub >> 16) & 1u)) & 0xffff0000u;
    return ua | ub;
}

// K1: blocks [0, EDGE_BLOCKS): bin 1024 edges each into coarse buckets.
//     blocks [EDGE_BLOCKS, EDGE_BLOCKS+CONV_BLOCKS): X fp32 -> bf16 planes.
// Record: rec.x = col | ((row & 255) << 24), rec.y = val bits
__global__ void setup_kernel(const float4* __restrict__ X4,
                             uint4* __restrict__ Xb,
                             const int4* __restrict__ rows4,
                             const int4* __restrict__ cols4,
                             const float4* __restrict__ vals4,
                             int* __restrict__ bucket_cnt,
                             uint2* __restrict__ bucket_buf) {
    __shared__ int hist[NBUCK];
    __shared__ int gbase[NBUCK];
    int tid = threadIdx.x;

    if (blockIdx.x < EDGE_BLOCKS) {
        for (int i = tid; i < NBUCK; i += 256) hist[i] = 0;
        __syncthreads();

        int e = blockIdx.x * 256 + tid;          // quad-edge index
        bool act = (e < N_EDGES / 4);
        int4 r, c; float4 v;
        int b0 = 0, b1 = 0, b2 = 0, b3 = 0;
        int k0 = 0, k1 = 0, k2 = 0, k3 = 0;
        if (act) {
            r = ntl_i4(&rows4[e]); c = ntl_i4(&cols4[e]); v = ntl_f4(&vals4[e]);
            b0 = r.x >> 8; b1 = r.y >> 8; b2 = r.z >> 8; b3 = r.w >> 8;
            k0 = atomicAdd(&hist[b0], 1);        // LDS atomics: no fabric
            k1 = atomicAdd(&hist[b1], 1);
            k2 = atomicAdd(&hist[b2], 1);
            k3 = atomicAdd(&hist[b3], 1);
        }
        __syncthreads();

        // one global atomic per (block, bucket)
        for (int i = tid; i < NBUCK; i += 256)
            gbase[i] = atomicAdd(&bucket_cnt[i], hist[i]);
        __syncthreads();

        if (act) {
            uint2 p;
            int d;
            d = gbase[b0] + k0;
            if (d < CAP) {
                p.x = (unsigned)c.x | ((unsigned)(r.x & 255) << 24);
                p.y = __float_as_uint(v.x);
                nts_u2(&bucket_buf[b0 * CAP + d], p);
            }
            d = gbase[b1] + k1;
            if (d < CAP) {
                p.x = (unsigned)c.y | ((unsigned)(r.y & 255) << 24);
                p.y = __float_as_uint(v.y);
                nts_u2(&bucket_buf[b1 * CAP + d], p);
            }
            d = gbase[b2] + k2;
            if (d < CAP) {
                p.x = (unsigned)c.z | ((unsigned)(r.z & 255) << 24);
                p.y = __float_as_uint(v.z);
                nts_u2(&bucket_buf[b2 * CAP + d], p);
            }
            d = gbase[b3] + k3;
            if (d < CAP) {
                p.x = (unsigned)c.w | ((unsigned)(r.w & 255) << 24);
                p.y = __float_as_uint(v.w);
                nts_u2(&bucket_buf[b3 * CAP + d], p);
            }
        }
    } else {
        int chunk = (blockIdx.x - EDGE_BLOCKS) * 256 + tid;
        if (chunk < NCHUNK) {
            float4 a = ntl_f4(&X4[chunk * 2]);
            float4 b = ntl_f4(&X4[chunk * 2 + 1]);
            uint4 o;
            o.x = packbf(a.x, a.y);
            o.y = packbf(a.z, a.w);
            o.z = packbf(b.x, b.y);
            o.w = packbf(b.z, b.w);
            int row = chunk / C16;
            int ct  = chunk % C16;
            // plane layout: plane s = [N][4 uint4]
            nts_u4(&Xb[(ct >> 2) * PLANE_U4 + row * 4 + (ct & 3)], o);
        }
    }
}

// K2: one block per bucket. LDS slot counters; writes in 128KB window.
__global__ void ell_build_kernel(const int* __restrict__ bucket_cnt,
                                 const uint2* __restrict__ bucket_buf,
                                 int2* __restrict__ ell,
                                 int* __restrict__ cnt) {
    __shared__ int lc[RPB];
    int b = blockIdx.x;
    int tid = threadIdx.x;
    if (tid < RPB) lc[tid] = 0;
    __syncthreads();

    int n = bucket_cnt[b];
    if (n > CAP) n = CAP;
    const uint2* buf = bucket_buf + b * CAP;
    for (int i = tid; i < n; i += 512) {
        uint2 rec = ntl_u2(&buf[i]);
        int rl = rec.x >> 24;
        int slot = atomicAdd(&lc[rl], 1);        // LDS atomic
        if (slot < PAD) {
            int2 p;
            p.x = (int)(rec.x & 0x00ffffffu);
            p.y = (int)rec.y;
            nts_i2(&ell[(b * RPB + rl) * PAD + slot], p);
        }
    }
    __syncthreads();
    if (tid < RPB) {
        int row = b * RPB + tid;
        if (row < N_NODES) {
            int d = lc[tid];
            cnt[row] = (d > PAD) ? PAD : d;
        }
    }
}

// Slice-pass SpMM. One thread per (row, 16B chunk within slice): 4 thr/row.
// Gathers (temporal, L2-resident plane) vs streams (non-temporal).
// MODE 0: ego_out = agg*(1+ego_in).
// MODE 1 (last layer): acc = (Xb + e1 + ego_in + e3) * 0.25, no ego_out.
template <int MODE>
__global__ void spmm_slice_kernel(const uint4* __restrict__ ego_in,
                                  uint4* __restrict__ ego_out,
                                  const int* __restrict__ cnt,
                                  const int4* __restrict__ ell4,
                                  const uint4* __restrict__ xb,
                                  const uint4* __restrict__ e1v,
                                  float4* __restrict__ acc,
                                  int slice) {
    int tid = blockIdx.x * blockDim.x + threadIdx.x;
    if (tid >= N_NODES * 4) return;
    int row = tid >> 2;
    int q   = tid & 3;

    const uint4* in_pl = ego_in + slice * PLANE_U4;

    int deg = cnt[row];
    const int4* ep = ell4 + row * (PAD / 2);

    float s0[8] = {0.f, 0.f, 0.f, 0.f, 0.f, 0.f, 0.f, 0.f};

    int j = 0;
    for (; j + 4 <= deg; j += 4) {
        int4 pA = ntl_i4(&ep[j >> 1]);
        int4 pB = ntl_i4(&ep[(j >> 1) + 1]);
        uint4 x0 = in_pl[(pA.x << 2) + q];
        uint4 x1 = in_pl[(pA.z << 2) + q];
        uint4 x2 = in_pl[(pB.x << 2) + q];
        uint4 x3 = in_pl[(pB.z << 2) + q];
        float v0 = __int_as_float(pA.y);
        float v1 = __int_as_float(pA.w);
        float v2 = __int_as_float(pB.y);
        float v3 = __int_as_float(pB.w);
        fma_bf8(s0, v0, x0);
        fma_bf8(s0, v1, x1);
        fma_bf8(s0, v2, x2);
        fma_bf8(s0, v3, x3);
    }
    for (; j + 2 <= deg; j += 2) {
        int4 pA = ntl_i4(&ep[j >> 1]);
        uint4 x0 = in_pl[(pA.x << 2) + q];
        uint4 x1 = in_pl[(pA.z << 2) + q];
        float v0 = __int_as_float(pA.y);
        float v1 = __int_as_float(pA.w);
        fma_bf8(s0, v0, x0);
        fma_bf8(s0, v1, x1);
    }
    if (j < deg) {
        int2 p = ntl_i2(&((const int2*)ell4)[row * PAD + j]);
        uint4 x0 = in_pl[(p.x << 2) + q];
        float v0 = __int_as_float(p.y);
        fma_bf8(s0, v0, x0);
    }

    int ib = (row << 2) + q;
    float e0[8];
    unpack8(e0, in_pl[ib]);
    float n0[8];
#pragma unroll
    for (int k = 0; k < 8; ++k)
        n0[k] = fmaf(s0[k], e0[k], s0[k]);   // s*(1+e)

    if (MODE == 0) {
        uint4 oa;
        oa.x = packbf(n0[0], n0[1]); oa.y = packbf(n0[2], n0[3]);
        oa.z = packbf(n0[4], n0[5]); oa.w = packbf(n0[6], n0[7]);
        nts_u4(&ego_out[slice * PLANE_U4 + ib], oa);
    } else {
        // acc = (X + e1 + e2 + e3) / 4 ; ego_in is e2, n is e3
        float x0[8], f0[8];
        unpack8(x0, ntl_u4(&xb[slice * PLANE_U4 + ib]));
        unpack8(f0, ntl_u4(&e1v[slice * PLANE_U4 + ib]));
        int ia = row * (EMB / 4) + slice * 8 + q * 2;
        float4 a0, a1;
        a0.x = (x0[0] + f0[0] + e0[0] + n0[0]) * 0.25f;
        a0.y = (x0[1] + f0[1] + e0[1] + n0[1]) * 0.25f;
        a0.z = (x0[2] + f0[2] + e0[2] + n0[2]) * 0.25f;
        a0.w = (x0[3] + f0[3] + e0[3] + n0[3]) * 0.25f;
        a1.x = (x0[4] + f0[4] + e0[4] + n0[4]) * 0.25f;
        a1.y = (x0[5] + f0[5] + e0[5] + n0[5]) * 0.25f;
        a1.z = (x0[6] + f0[6] + e0[6] + n0[6]) * 0.25f;
        a1.w = (x0[7] + f0[7] + e0[7] + n0[7]) * 0.25f;
        nts_f4(&acc[ia], a0);
        nts_f4(&acc[ia + 1], a1);
    }
}

extern "C" void kernel_launch(void* const* d_in, const int* in_sizes, int n_in,
                              void* d_out, int out_size, void* d_ws, size_t ws_size,
                              hipStream_t stream) {
    const float* X    = (const float*)d_in[0];
    const float* vals = (const float*)d_in[1];
    const int*   rows = (const int*)d_in[2];
    const int*   cols = (const int*)d_in[3];

    const size_t nodeb_bytes = (size_t)NCHUNK * sizeof(uint4);       // 9.6 MB
    const size_t ell_bytes   = (size_t)N_NODES * PAD * sizeof(int2); // 25.6 MB
    const size_t cnt_bytes   = (size_t)N_NODES * sizeof(int);        // 0.2 MB

    float* acc = (float*)d_out;

    char* w = (char*)d_ws;
    uint4* Xb    = (uint4*)w;  w += nodeb_bytes;   // 3 planes
    uint4* ego_a = (uint4*)w;  w += nodeb_bytes;   // e1 planes
    uint4* ego_b = (uint4*)w;  w += nodeb_bytes;   // e2 planes
    int2*  ell   = (int2*)w;   w += ell_bytes;
    int*   cnt   = (int*)w;    w += cnt_bytes;

    // bucket scratch aliases ego_a/ego_b: consumed by K2 before spmm writes them
    uint2* bucket_buf = (uint2*)ego_a;               // 7.84 MB <= 9.6 MB
    int*   bucket_cnt = (int*)ego_b;                 // 784 B

    hipMemsetAsync(bucket_cnt, 0, NBUCK * sizeof(int), stream);

    setup_kernel<<<EDGE_BLOCKS + CONV_BLOCKS, 256, 0, stream>>>(
        (const float4*)X, Xb,
        (const int4*)rows, (const int4*)cols, (const float4*)vals,
        bucket_cnt, bucket_buf);

    ell_build_kernel<<<NBUCK, 512, 0, stream>>>(bucket_cnt, bucket_buf, ell, cnt);

    const int blocks = (N_NODES * 4 + 255) / 256;

    // layer 1: Xb -> e1
    for (int s = 0; s < NSLICE; ++s)
        spmm_slice_kernel<0><<<blocks, 256, 0, stream>>>(
            Xb, ego_a, cnt, (const int4*)ell, nullptr, nullptr, nullptr, s);
    // layer 2: e1 -> e2
    for (int s = 0; s < NSLICE; ++s)
        spmm_slice_kernel<0><<<blocks, 256, 0, stream>>>(
            ego_a, ego_b, cnt, (const int4*)ell, nullptr, nullptr, nullptr, s);
    // layer 3: e2 -> acc = (X + e1 + e2 + e3)/4, e3 in regs only
    for (int s = 0; s < NSLICE; ++s)
        spmm_slice_kernel<1><<<blocks, 256, 0, stream>>>(
            ego_b, nullptr, cnt, (const int4*)ell, Xb, ego_a, (float4*)acc, s);
}

// Round 7
// 198.863 us; speedup vs baseline: 1.4918x; 1.4918x over previous
//
#include <hip/hip_runtime.h>
#include <hip/hip_bf16.h>

// GNN forward: 3 layers of COO SpMM + gating, mean over layer embeddings.
// N=50000, E=800000, D=96.
//
// Round-11: r10 retry with safe LDS footprint (r10's bench died twice;
// its 129KB static LDS was the only risky novelty).
//  Same theory: ell_build's scattered 8B ELL writes (~800k random
//  write-sectors ~13us at the measured ~60 sectors/us chip rate) ->
//  stage bucket ELL image in LDS, flush coalesced.
//  Change vs r10: buckets of 128 rows (row>>7, NBUCK=391, CAP=2500),
//  LDS image 128x64x8B = 64KB + 0.5KB counters. 2 wg/CU occupancy.
//  Everything else identical to round-7 (best verified, 190.1us).

#define N_NODES 50000
#define N_EDGES 800000
#define EMB 96
#define C16 12                    // 16B bf16 chunks per row
#define TPR 6                     // threads per row (2 chunks each)
#define LAYER_NUM 3
#define PAD 64                    // ELL slots per row
#define NCHUNK (N_NODES * C16)    // 600000 bf16 chunks total

#define NBUCK 391                 // ceil(50000/128) coarse buckets (row>>7)
#define RPB 128                   // rows per bucket
#define CAP 2500                  // record capacity per bucket (mean 2046, +10 sigma)
#define EDGE_BLOCKS 782           // ceil(200000 quad-edges / 256)
#define CONV_BLOCKS 2344          // ceil(600000 chunks / 256)

__device__ __forceinline__ float bflo(unsigned u) { return __uint_as_float(u << 16); }
__device__ __forceinline__ float bfhi(unsigned u) { return __uint_as_float(u & 0xffff0000u); }

__device__ __forceinline__ void fma_bf8(float* s, float v, const uint4& u) {
    s[0] = fmaf(v, bflo(u.x), s[0]);
    s[1] = fmaf(v, bfhi(u.x), s[1]);
    s[2] = fmaf(v, bflo(u.y), s[2]);
    s[3] = fmaf(v, bfhi(u.y), s[3]);
    s[4] = fmaf(v, bflo(u.z), s[4]);
    s[5] = fmaf(v, bfhi(u.z), s[5]);
    s[6] = fmaf(v, bflo(u.w), s[6]);
    s[7] = fmaf(v, bfhi(u.w), s[7]);
}

__device__ __forceinline__ void unpack8(float* d, const uint4& u) {
    d[0] = bflo(u.x); d[1] = bfhi(u.x);
    d[2] = bflo(u.y); d[3] = bfhi(u.y);
    d[4] = bflo(u.z); d[5] = bfhi(u.z);
    d[6] = bflo(u.w); d[7] = bfhi(u.w);
}

// RNE pack: a -> low 16, b -> high 16
__device__ __forceinline__ unsigned packbf(float a, float b) {
    unsigned ua = __float_as_uint(a);
    unsigned ub = __float_as_uint(b);
    ua = (ua + 0x7fffu + ((ua >> 16) & 1u)) >> 16;
    ub = (ub + 0x7fffu + ((ub >> 16) & 1u)) & 0xffff0000u;
    return ua | ub;
}

// K1: blocks [0, EDGE_BLOCKS): bin 1024 edges each into coarse buckets.
//     blocks [EDGE_BLOCKS, EDGE_BLOCKS+CONV_BLOCKS): X fp32 -> bf16 convert.
// Record: rec.x = col | ((row & 127) << 24), rec.y = val bits
__global__ void setup_kernel(const float4* __restrict__ X4,
                             uint4* __restrict__ Xb,
                             const int4* __restrict__ rows4,
                             const int4* __restrict__ cols4,
                             const float4* __restrict__ vals4,
                             int* __restrict__ bucket_cnt,
                             uint2* __restrict__ bucket_buf) {
    __shared__ int hist[NBUCK];
    __shared__ int gbase[NBUCK];
    int tid = threadIdx.x;

    if (blockIdx.x < EDGE_BLOCKS) {
        for (int i = tid; i < NBUCK; i += 256) hist[i] = 0;
        __syncthreads();

        int e = blockIdx.x * 256 + tid;          // quad-edge index
        bool act = (e < N_EDGES / 4);
        int4 r, c; float4 v;
        int b0 = 0, b1 = 0, b2 = 0, b3 = 0;
        int k0 = 0, k1 = 0, k2 = 0, k3 = 0;
        if (act) {
            r = rows4[e]; c = cols4[e]; v = vals4[e];
            b0 = r.x >> 7; b1 = r.y >> 7; b2 = r.z >> 7; b3 = r.w >> 7;
            k0 = atomicAdd(&hist[b0], 1);        // LDS atomics: no fabric
            k1 = atomicAdd(&hist[b1], 1);
            k2 = atomicAdd(&hist[b2], 1);
            k3 = atomicAdd(&hist[b3], 1);
        }
        __syncthreads();

        // one global atomic per (block, bucket)
        for (int i = tid; i < NBUCK; i += 256)
            gbase[i] = atomicAdd(&bucket_cnt[i], hist[i]);
        __syncthreads();

        if (act) {
            uint2 p;
            int d;
            d = gbase[b0] + k0;
            if (d < CAP) {
                p.x = (unsigned)c.x | ((unsigned)(r.x & 127) << 24);
                p.y = __float_as_uint(v.x);
                bucket_buf[b0 * CAP + d] = p;
            }
            d = gbase[b1] + k1;
            if (d < CAP) {
                p.x = (unsigned)c.y | ((unsigned)(r.y & 127) << 24);
                p.y = __float_as_uint(v.y);
                bucket_buf[b1 * CAP + d] = p;
            }
            d = gbase[b2] + k2;
            if (d < CAP) {
                p.x = (unsigned)c.z | ((unsigned)(r.z & 127) << 24);
                p.y = __float_as_uint(v.z);
                bucket_buf[b2 * CAP + d] = p;
            }
            d = gbase[b3] + k3;
            if (d < CAP) {
                p.x = (unsigned)c.w | ((unsigned)(r.w & 127) << 24);
                p.y = __float_as_uint(v.w);
                bucket_buf[b3 * CAP + d] = p;
            }
        }
    } else {
        int chunk = (blockIdx.x - EDGE_BLOCKS) * 256 + tid;
        if (chunk < NCHUNK) {
            float4 a = X4[chunk * 2];
            float4 b = X4[chunk * 2 + 1];
            uint4 o;
            o.x = packbf(a.x, a.y);
            o.y = packbf(a.z, a.w);
            o.z = packbf(b.x, b.y);
            o.w = packbf(b.z, b.w);
            Xb[chunk] = o;
        }
    }
}

// K2: one block per bucket. Stage the bucket's ELL image in LDS
// (128 rows x 64 slots x 8B = 64KB + 0.5KB counters), then stream it
// out coalesced: ~800k scattered 8B write-sectors -> ~100k sequential.
// LDS slot counters, zero global atomics. Emits compact cnt[row].
__global__ void ell_build_kernel(const int* __restrict__ bucket_cnt,
                                 const uint2* __restrict__ bucket_buf,
                                 int2* __restrict__ ell,
                                 int* __restrict__ cnt) {
    __shared__ uint2 arr[RPB * PAD];   // 64 KB ELL image
    __shared__ int   lc[RPB];          // 0.5 KB counters
    int b = blockIdx.x;
    int tid = threadIdx.x;
    if (tid < RPB) lc[tid] = 0;
    __syncthreads();

    int n = bucket_cnt[b];
    if (n > CAP) n = CAP;
    const uint2* buf = bucket_buf + b * CAP;
    for (int i = tid; i < n; i += 512) {
        uint2 rec = buf[i];
        int rl = rec.x >> 24;
        int slot = atomicAdd(&lc[rl], 1);        // LDS atomic
        if (slot < PAD)
            arr[(rl << 6) + slot] = make_uint2(rec.x & 0x00ffffffu, rec.y);
    }
    __syncthreads();

    // coalesced flush: slot s of row rl at linear j = rl*64+s; only s<deg.
    // rows >= N_NODES have lc==0 so nothing is written for them.
    int2* ell_b = ell + (size_t)b * RPB * PAD;
    for (int j = tid; j < RPB * PAD; j += 512) {
        int rl = j >> 6;
        int s  = j & (PAD - 1);
        int d  = lc[rl];
        if (d > PAD) d = PAD;
        if (s < d) {
            uint2 a = arr[j];
            ell_b[j] = make_int2((int)a.x, (int)a.y);
        }
    }
    if (tid < RPB) {
        int row = b * RPB + tid;
        if (row < N_NODES) {
            int d = lc[tid];
            cnt[row] = (d > PAD) ? PAD : d;
        }
    }
}

// One thread per (row, pair-of-16B-chunks): chunks ct and ct+TPR.
// MODE 0: ego_out = agg*(1+ego_in); acc untouched.
// MODE 1 (last layer): no ego_out; acc = (Xb + e1 + ego_in + e3) * 0.25.
template <int MODE>
__global__ void spmm_fused_kernel(const uint4* __restrict__ ego_in,
                                  uint4* __restrict__ ego_out,
                                  const int* __restrict__ cnt,
                                  const int4* __restrict__ ell4,
                                  const uint4* __restrict__ xb,
                                  const uint4* __restrict__ e1v,
                                  float4* __restrict__ acc) {
    int tid = blockIdx.x * blockDim.x + threadIdx.x;
    if (tid >= N_NODES * TPR) return;
    int row = tid / TPR;
    int ct  = tid % TPR;

    int deg = cnt[row];
    const int4* ep = ell4 + row * (PAD / 2);

    float s0[8] = {0.f, 0.f, 0.f, 0.f, 0.f, 0.f, 0.f, 0.f};
    float s1[8] = {0.f, 0.f, 0.f, 0.f, 0.f, 0.f, 0.f, 0.f};

    int j = 0;
    for (; j + 4 <= deg; j += 4) {
        int4 pA = ep[j >> 1];
        int4 pB = ep[(j >> 1) + 1];
        const uint4* b0 = ego_in + pA.x * C16;
        const uint4* b1 = ego_in + pA.z * C16;
        const uint4* b2 = ego_in + pB.x * C16;
        const uint4* b3 = ego_in + pB.z * C16;
        uint4 x0a = b0[ct], x0b = b0[ct + TPR];
        uint4 x1a = b1[ct], x1b = b1[ct + TPR];
        uint4 x2a = b2[ct], x2b = b2[ct + TPR];
        uint4 x3a = b3[ct], x3b = b3[ct + TPR];
        float v0 = __int_as_float(pA.y);
        float v1 = __int_as_float(pA.w);
        float v2 = __int_as_float(pB.y);
        float v3 = __int_as_float(pB.w);
        fma_bf8(s0, v0, x0a); fma_bf8(s1, v0, x0b);
        fma_bf8(s0, v1, x1a); fma_bf8(s1, v1, x1b);
        fma_bf8(s0, v2, x2a); fma_bf8(s1, v2, x2b);
        fma_bf8(s0, v3, x3a); fma_bf8(s1, v3, x3b);
    }
    for (; j + 2 <= deg; j += 2) {
        int4 pA = ep[j >> 1];
        const uint4* b0 = ego_in + pA.x * C16;
        const uint4* b1 = ego_in + pA.z * C16;
        uint4 x0a = b0[ct], x0b = b0[ct + TPR];
        uint4 x1a = b1[ct], x1b = b1[ct + TPR];
        float v0 = __int_as_float(pA.y);
        float v1 = __int_as_float(pA.w);
        fma_bf8(s0, v0, x0a); fma_bf8(s1, v0, x0b);
        fma_bf8(s0, v1, x1a); fma_bf8(s1, v1, x1b);
    }
    if (j < deg) {
        int2 p = ((const int2*)ell4)[row * PAD + j];
        const uint4* b0 = ego_in + p.x * C16;
        uint4 x0a = b0[ct], x0b = b0[ct + TPR];
        float v0 = __int_as_float(p.y);
        fma_bf8(s0, v0, x0a); fma_bf8(s1, v0, x0b);
    }

    int ib = row * C16 + ct;
    uint4 ea = ego_in[ib];
    uint4 eb = ego_in[ib + TPR];
    float e0[8], e1[8];
    unpack8(e0, ea);
    unpack8(e1, eb);
    float n0[8], n1[8];
#pragma unroll
    for (int k = 0; k < 8; ++k) {
        n0[k] = fmaf(s0[k], e0[k], s0[k]);   // s*(1+e)
        n1[k] = fmaf(s1[k], e1[k], s1[k]);
    }

    if (MODE == 0) {
        uint4 oa, ob;
        oa.x = packbf(n0[0], n0[1]); oa.y = packbf(n0[2], n0[3]);
        oa.z = packbf(n0[4], n0[5]); oa.w = packbf(n0[6], n0[7]);
        ob.x = packbf(n1[0], n1[1]); ob.y = packbf(n1[2], n1[3]);
        ob.z = packbf(n1[4], n1[5]); ob.w = packbf(n1[6], n1[7]);
        ego_out[ib]       = oa;
        ego_out[ib + TPR] = ob;
    } else {
        // acc = (X + e1 + e2 + e3) / 4 ; ego_in is e2, n is e3
        float x0[8], x1[8], f0[8], f1[8];
        unpack8(x0, xb[ib]);
        unpack8(x1, xb[ib + TPR]);
        unpack8(f0, e1v[ib]);
        unpack8(f1, e1v[ib + TPR]);
        int ia = row * (EMB / 4) + ct * 2;   // chunks 2ct, 2ct+1, 2ct+12, 2ct+13
        float4 a0, a1, a2, a3;
        a0.x = (x0[0] + f0[0] + e0[0] + n0[0]) * 0.25f;
        a0.y = (x0[1] + f0[1] + e0[1] + n0[1]) * 0.25f;
        a0.z = (x0[2] + f0[2] + e0[2] + n0[2]) * 0.25f;
        a0.w = (x0[3] + f0[3] + e0[3] + n0[3]) * 0.25f;
        a1.x = (x0[4] + f0[4] + e0[4] + n0[4]) * 0.25f;
        a1.y = (x0[5] + f0[5] + e0[5] + n0[5]) * 0.25f;
        a1.z = (x0[6] + f0[6] + e0[6] + n0[6]) * 0.25f;
        a1.w = (x0[7] + f0[7] + e0[7] + n0[7]) * 0.25f;
        a2.x = (x1[0] + f1[0] + e1[0] + n1[0]) * 0.25f;
        a2.y = (x1[1] + f1[1] + e1[1] + n1[1]) * 0.25f;
        a2.z = (x1[2] + f1[2] + e1[2] + n1[2]) * 0.25f;
        a2.w = (x1[3] + f1[3] + e1[3] + n1[3]) * 0.25f;
        a3.x = (x1[4] + f1[4] + e1[4] + n1[4]) * 0.25f;
        a3.y = (x1[5] + f1[5] + e1[5] + n1[5]) * 0.25f;
        a3.z = (x1[6] + f1[6] + e1[6] + n1[6]) * 0.25f;
        a3.w = (x1[7] + f1[7] + e1[7] + n1[7]) * 0.25f;
        acc[ia]      = a0;
        acc[ia + 1]  = a1;
        acc[ia + 12] = a2;
        acc[ia + 13] = a3;
    }
}

extern "C" void kernel_launch(void* const* d_in, const int* in_sizes, int n_in,
                              void* d_out, int out_size, void* d_ws, size_t ws_size,
                              hipStream_t stream) {
    const float* X    = (const float*)d_in[0];
    const float* vals = (const float*)d_in[1];
    const int*   rows = (const int*)d_in[2];
    const int*   cols = (const int*)d_in[3];

    const size_t nodeb_bytes = (size_t)NCHUNK * sizeof(uint4);       // 9.6 MB
    const size_t ell_bytes   = (size_t)N_NODES * PAD * sizeof(int2); // 25.6 MB
    const size_t cnt_bytes   = (size_t)N_NODES * sizeof(int);        // 0.2 MB

    float* acc = (float*)d_out;

    char* w = (char*)d_ws;
    uint4* Xb    = (uint4*)w;  w += nodeb_bytes;   // bf16 node rows (AoS, 192B)
    uint4* ego_a = (uint4*)w;  w += nodeb_bytes;   // e1
    uint4* ego_b = (uint4*)w;  w += nodeb_bytes;   // e2
    int2*  ell   = (int2*)w;   w += ell_bytes;
    int*   cnt   = (int*)w;    w += cnt_bytes;

    // bucket scratch aliases ego_a/ego_b: consumed by K2 before spmm writes them
    uint2* bucket_buf = (uint2*)ego_a;               // 391*2500*8 = 7.82 MB <= 9.6 MB
    int*   bucket_cnt = (int*)ego_b;                 // 1.6 KB

    hipMemsetAsync(bucket_cnt, 0, NBUCK * sizeof(int), stream);

    setup_kernel<<<EDGE_BLOCKS + CONV_BLOCKS, 256, 0, stream>>>(
        (const float4*)X, Xb,
        (const int4*)rows, (const int4*)cols, (const float4*)vals,
        bucket_cnt, bucket_buf);

    ell_build_kernel<<<NBUCK, 512, 0, stream>>>(bucket_cnt, bucket_buf, ell, cnt);

    const int blocks = (N_NODES * TPR + 255) / 256;

    // layer 1: Xb -> e1
    spmm_fused_kernel<0><<<blocks, 256, 0, stream>>>(
        Xb, ego_a, cnt, (const int4*)ell, nullptr, nullptr, nullptr);
    // layer 2: e1 -> e2
    spmm_fused_kernel<0><<<blocks, 256, 0, stream>>>(
        ego_a, ego_b, cnt, (const int4*)ell, nullptr, nullptr, nullptr);
    // layer 3: e2 -> acc = (X + e1 + e2 + e3)/4, e3 in regs only
    spmm_fused_kernel<1><<<blocks, 256, 0, stream>>>(
        ego_b, nullptr, cnt, (const int4*)ell, Xb, ego_a, (float4*)acc);
}

// Round 8
// 189.945 us; speedup vs baseline: 1.5618x; 1.0470x over previous
//
#include <hip/hip_runtime.h>
#include <hip/hip_bf16.h>

// GNN forward: 3 layers of COO SpMM + gating, mean over layer embeddings.
// N=50000, E=800000, D=96.
//
// Round-12: exact round-7 structure (best verified, 190.1us) + bucket_cnt
// padded to one counter per 64B line.
//  Evidence: r10/r11 (coalesced ELL flush) REGRESSED -> scattered ELL writes
//  were already absorbed by L2 write-combining; reverted. New target: K1's
//  bucket reservation packs 153k device-scope atomicAdds (782 blocks x 196
//  buckets) into 13 cache lines; same-line RMWs serialize in TCC (~12k per
//  line) and every block waits on its reservation -> est. 10-35us hidden
//  serial tail. Fix: CNT_PAD=16 (one counter per 64B line) -> 196 parallel
//  line-streams of 782 RMWs each. Same fix class as round-5's cnt padding.
//  Single-variable change vs r7.

#define N_NODES 50000
#define N_EDGES 800000
#define EMB 96
#define C16 12                    // 16B bf16 chunks per row
#define TPR 6                     // threads per row (2 chunks each)
#define LAYER_NUM 3
#define PAD 64                    // ELL slots per row
#define NCHUNK (N_NODES * C16)    // 600000 bf16 chunks total

#define NBUCK 196                 // ceil(50000/256) coarse buckets (row>>8)
#define RPB 256                   // rows per bucket
#define CAP 5000                  // record capacity per bucket
#define CNT_PAD 16                // ints per counter: one 64B line each
#define EDGE_BLOCKS 782           // ceil(200000 quad-edges / 256)
#define CONV_BLOCKS 2344          // ceil(600000 chunks / 256)

__device__ __forceinline__ float bflo(unsigned u) { return __uint_as_float(u << 16); }
__device__ __forceinline__ float bfhi(unsigned u) { return __uint_as_float(u & 0xffff0000u); }

__device__ __forceinline__ void fma_bf8(float* s, float v, const uint4& u) {
    s[0] = fmaf(v, bflo(u.x), s[0]);
    s[1] = fmaf(v, bfhi(u.x), s[1]);
    s[2] = fmaf(v, bflo(u.y), s[2]);
    s[3] = fmaf(v, bfhi(u.y), s[3]);
    s[4] = fmaf(v, bflo(u.z), s[4]);
    s[5] = fmaf(v, bfhi(u.z), s[5]);
    s[6] = fmaf(v, bflo(u.w), s[6]);
    s[7] = fmaf(v, bfhi(u.w), s[7]);
}

__device__ __forceinline__ void unpack8(float* d, const uint4& u) {
    d[0] = bflo(u.x); d[1] = bfhi(u.x);
    d[2] = bflo(u.y); d[3] = bfhi(u.y);
    d[4] = bflo(u.z); d[5] = bfhi(u.z);
    d[6] = bflo(u.w); d[7] = bfhi(u.w);
}

// RNE pack: a -> low 16, b -> high 16
__device__ __forceinline__ unsigned packbf(float a, float b) {
    unsigned ua = __float_as_uint(a);
    unsigned ub = __float_as_uint(b);
    ua = (ua + 0x7fffu + ((ua >> 16) & 1u)) >> 16;
    ub = (ub + 0x7fffu + ((ub >> 16) & 1u)) & 0xffff0000u;
    return ua | ub;
}

// K1: blocks [0, EDGE_BLOCKS): bin 1024 edges each into coarse buckets.
//     blocks [EDGE_BLOCKS, EDGE_BLOCKS+CONV_BLOCKS): X fp32 -> bf16 convert.
// Record: rec.x = col | ((row & 255) << 24), rec.y = val bits
__global__ void setup_kernel(const float4* __restrict__ X4,
                             uint4* __restrict__ Xb,
                             const int4* __restrict__ rows4,
                             const int4* __restrict__ cols4,
                             const float4* __restrict__ vals4,
                             int* __restrict__ bucket_cnt,
                             uint2* __restrict__ bucket_buf) {
    __shared__ int hist[NBUCK];
    __shared__ int gbase[NBUCK];
    int tid = threadIdx.x;

    if (blockIdx.x < EDGE_BLOCKS) {
        for (int i = tid; i < NBUCK; i += 256) hist[i] = 0;
        __syncthreads();

        int e = blockIdx.x * 256 + tid;          // quad-edge index
        bool act = (e < N_EDGES / 4);
        int4 r, c; float4 v;
        int b0 = 0, b1 = 0, b2 = 0, b3 = 0;
        int k0 = 0, k1 = 0, k2 = 0, k3 = 0;
        if (act) {
            r = rows4[e]; c = cols4[e]; v = vals4[e];
            b0 = r.x >> 8; b1 = r.y >> 8; b2 = r.z >> 8; b3 = r.w >> 8;
            k0 = atomicAdd(&hist[b0], 1);        // LDS atomics: no fabric
            k1 = atomicAdd(&hist[b1], 1);
            k2 = atomicAdd(&hist[b2], 1);
            k3 = atomicAdd(&hist[b3], 1);
        }
        __syncthreads();

        // one global atomic per (block, bucket); counters padded to 64B lines
        for (int i = tid; i < NBUCK; i += 256)
            gbase[i] = atomicAdd(&bucket_cnt[i * CNT_PAD], hist[i]);
        __syncthreads();

        if (act) {
            uint2 p;
            int d;
            d = gbase[b0] + k0;
            if (d < CAP) {
                p.x = (unsigned)c.x | ((unsigned)(r.x & 255) << 24);
                p.y = __float_as_uint(v.x);
                bucket_buf[b0 * CAP + d] = p;
            }
            d = gbase[b1] + k1;
            if (d < CAP) {
                p.x = (unsigned)c.y | ((unsigned)(r.y & 255) << 24);
                p.y = __float_as_uint(v.y);
                bucket_buf[b1 * CAP + d] = p;
            }
            d = gbase[b2] + k2;
            if (d < CAP) {
                p.x = (unsigned)c.z | ((unsigned)(r.z & 255) << 24);
                p.y = __float_as_uint(v.z);
                bucket_buf[b2 * CAP + d] = p;
            }
            d = gbase[b3] + k3;
            if (d < CAP) {
                p.x = (unsigned)c.w | ((unsigned)(r.w & 255) << 24);
                p.y = __float_as_uint(v.w);
                bucket_buf[b3 * CAP + d] = p;
            }
        }
    } else {
        int chunk = (blockIdx.x - EDGE_BLOCKS) * 256 + tid;
        if (chunk < NCHUNK) {
            float4 a = X4[chunk * 2];
            float4 b = X4[chunk * 2 + 1];
            uint4 o;
            o.x = packbf(a.x, a.y);
            o.y = packbf(a.z, a.w);
            o.z = packbf(b.x, b.y);
            o.w = packbf(b.z, b.w);
            Xb[chunk] = o;
        }
    }
}

// K2: one block per bucket. LDS slot counters (zero global atomics);
// ELL writes confined to this bucket's 128KB window; emits compact cnt[row].
__global__ void ell_build_kernel(const int* __restrict__ bucket_cnt,
                                 const uint2* __restrict__ bucket_buf,
                                 int2* __restrict__ ell,
                                 int* __restrict__ cnt) {
    __shared__ int lc[RPB];
    int b = blockIdx.x;
    int tid = threadIdx.x;
    if (tid < RPB) lc[tid] = 0;
    __syncthreads();

    int n = bucket_cnt[b * CNT_PAD];
    if (n > CAP) n = CAP;
    const uint2* buf = bucket_buf + b * CAP;
    for (int i = tid; i < n; i += 512) {
        uint2 rec = buf[i];
        int rl = rec.x >> 24;
        int slot = atomicAdd(&lc[rl], 1);        // LDS atomic
        if (slot < PAD) {
            int2 p;
            p.x = (int)(rec.x & 0x00ffffffu);
            p.y = (int)rec.y;
            ell[(b * RPB + rl) * PAD + slot] = p;
        }
    }
    __syncthreads();
    if (tid < RPB) {
        int row = b * RPB + tid;
        if (row < N_NODES) {
            int d = lc[tid];
            cnt[row] = (d > PAD) ? PAD : d;
        }
    }
}

// One thread per (row, pair-of-16B-chunks): chunks ct and ct+TPR.
// MODE 0: ego_out = agg*(1+ego_in); acc untouched.
// MODE 1 (last layer): no ego_out; acc = (Xb + e1 + ego_in + e3) * 0.25.
template <int MODE>
__global__ void spmm_fused_kernel(const uint4* __restrict__ ego_in,
                                  uint4* __restrict__ ego_out,
                                  const int* __restrict__ cnt,
                                  const int4* __restrict__ ell4,
                                  const uint4* __restrict__ xb,
                                  const uint4* __restrict__ e1v,
                                  float4* __restrict__ acc) {
    int tid = blockIdx.x * blockDim.x + threadIdx.x;
    if (tid >= N_NODES * TPR) return;
    int row = tid / TPR;
    int ct  = tid % TPR;

    int deg = cnt[row];
    const int4* ep = ell4 + row * (PAD / 2);

    float s0[8] = {0.f, 0.f, 0.f, 0.f, 0.f, 0.f, 0.f, 0.f};
    float s1[8] = {0.f, 0.f, 0.f, 0.f, 0.f, 0.f, 0.f, 0.f};

    int j = 0;
    for (; j + 4 <= deg; j += 4) {
        int4 pA = ep[j >> 1];
        int4 pB = ep[(j >> 1) + 1];
        const uint4* b0 = ego_in + pA.x * C16;
        const uint4* b1 = ego_in + pA.z * C16;
        const uint4* b2 = ego_in + pB.x * C16;
        const uint4* b3 = ego_in + pB.z * C16;
        uint4 x0a = b0[ct], x0b = b0[ct + TPR];
        uint4 x1a = b1[ct], x1b = b1[ct + TPR];
        uint4 x2a = b2[ct], x2b = b2[ct + TPR];
        uint4 x3a = b3[ct], x3b = b3[ct + TPR];
        float v0 = __int_as_float(pA.y);
        float v1 = __int_as_float(pA.w);
        float v2 = __int_as_float(pB.y);
        float v3 = __int_as_float(pB.w);
        fma_bf8(s0, v0, x0a); fma_bf8(s1, v0, x0b);
        fma_bf8(s0, v1, x1a); fma_bf8(s1, v1, x1b);
        fma_bf8(s0, v2, x2a); fma_bf8(s1, v2, x2b);
        fma_bf8(s0, v3, x3a); fma_bf8(s1, v3, x3b);
    }
    for (; j + 2 <= deg; j += 2) {
        int4 pA = ep[j >> 1];
        const uint4* b0 = ego_in + pA.x * C16;
        const uint4* b1 = ego_in + pA.z * C16;
        uint4 x0a = b0[ct], x0b = b0[ct + TPR];
        uint4 x1a = b1[ct], x1b = b1[ct + TPR];
        float v0 = __int_as_float(pA.y);
        float v1 = __int_as_float(pA.w);
        fma_bf8(s0, v0, x0a); fma_bf8(s1, v0, x0b);
        fma_bf8(s0, v1, x1a); fma_bf8(s1, v1, x1b);
    }
    if (j < deg) {
        int2 p = ((const int2*)ell4)[row * PAD + j];
        const uint4* b0 = ego_in + p.x * C16;
        uint4 x0a = b0[ct], x0b = b0[ct + TPR];
        float v0 = __int_as_float(p.y);
        fma_bf8(s0, v0, x0a); fma_bf8(s1, v0, x0b);
    }

    int ib = row * C16 + ct;
    uint4 ea = ego_in[ib];
    uint4 eb = ego_in[ib + TPR];
    float e0[8], e1[8];
    unpack8(e0, ea);
    unpack8(e1, eb);
    float n0[8], n1[8];
#pragma unroll
    for (int k = 0; k < 8; ++k) {
        n0[k] = fmaf(s0[k], e0[k], s0[k]);   // s*(1+e)
        n1[k] = fmaf(s1[k], e1[k], s1[k]);
    }

    if (MODE == 0) {
        uint4 oa, ob;
        oa.x = packbf(n0[0], n0[1]); oa.y = packbf(n0[2], n0[3]);
        oa.z = packbf(n0[4], n0[5]); oa.w = packbf(n0[6], n0[7]);
        ob.x = packbf(n1[0], n1[1]); ob.y = packbf(n1[2], n1[3]);
        ob.z = packbf(n1[4], n1[5]); ob.w = packbf(n1[6], n1[7]);
        ego_out[ib]       = oa;
        ego_out[ib + TPR] = ob;
    } else {
        // acc = (X + e1 + e2 + e3) / 4 ; ego_in is e2, n is e3
        float x0[8], x1[8], f0[8], f1[8];
        unpack8(x0, xb[ib]);
        unpack8(x1, xb[ib + TPR]);
        unpack8(f0, e1v[ib]);
        unpack8(f1, e1v[ib + TPR]);
        int ia = row * (EMB / 4) + ct * 2;   // chunks 2ct, 2ct+1, 2ct+12, 2ct+13
        float4 a0, a1, a2, a3;
        a0.x = (x0[0] + f0[0] + e0[0] + n0[0]) * 0.25f;
        a0.y = (x0[1] + f0[1] + e0[1] + n0[1]) * 0.25f;
        a0.z = (x0[2] + f0[2] + e0[2] + n0[2]) * 0.25f;
        a0.w = (x0[3] + f0[3] + e0[3] + n0[3]) * 0.25f;
        a1.x = (x0[4] + f0[4] + e0[4] + n0[4]) * 0.25f;
        a1.y = (x0[5] + f0[5] + e0[5] + n0[5]) * 0.25f;
        a1.z = (x0[6] + f0[6] + e0[6] + n0[6]) * 0.25f;
        a1.w = (x0[7] + f0[7] + e0[7] + n0[7]) * 0.25f;
        a2.x = (x1[0] + f1[0] + e1[0] + n1[0]) * 0.25f;
        a2.y = (x1[1] + f1[1] + e1[1] + n1[1]) * 0.25f;
        a2.z = (x1[2] + f1[2] + e1[2] + n1[2]) * 0.25f;
        a2.w = (x1[3] + f1[3] + e1[3] + n1[3]) * 0.25f;
        a3.x = (x1[4] + f1[4] + e1[4] + n1[4]) * 0.25f;
        a3.y = (x1[5] + f1[5] + e1[5] + n1[5]) * 0.25f;
        a3.z = (x1[6] + f1[6] + e1[6] + n1[6]) * 0.25f;
        a3.w = (x1[7] + f1[7] + e1[7] + n1[7]) * 0.25f;
        acc[ia]      = a0;
        acc[ia + 1]  = a1;
        acc[ia + 12] = a2;
        acc[ia + 13] = a3;
    }
}

extern "C" void kernel_launch(void* const* d_in, const int* in_sizes, int n_in,
                              void* d_out, int out_size, void* d_ws, size_t ws_size,
                              hipStream_t stream) {
    const float* X    = (const float*)d_in[0];
    const float* vals = (const float*)d_in[1];
    const int*   rows = (const int*)d_in[2];
    const int*   cols = (const int*)d_in[3];

    const size_t nodeb_bytes = (size_t)NCHUNK * sizeof(uint4);       // 9.6 MB
    const size_t ell_bytes   = (size_t)N_NODES * PAD * sizeof(int2); // 25.6 MB
    const size_t cnt_bytes   = (size_t)N_NODES * sizeof(int);        // 0.2 MB

    float* acc = (float*)d_out;

    char* w = (char*)d_ws;
    uint4* Xb    = (uint4*)w;  w += nodeb_bytes;   // bf16 node rows (AoS, 192B)
    uint4* ego_a = (uint4*)w;  w += nodeb_bytes;   // e1
    uint4* ego_b = (uint4*)w;  w += nodeb_bytes;   // e2
    int2*  ell   = (int2*)w;   w += ell_bytes;
    int*   cnt   = (int*)w;    w += cnt_bytes;

    // bucket scratch aliases ego_a/ego_b: consumed by K2 before spmm writes them
    uint2* bucket_buf = (uint2*)ego_a;               // 196*5000*8 = 7.84 MB <= 9.6 MB
    int*   bucket_cnt = (int*)ego_b;                 // 196*16*4 = 12.5 KB

    hipMemsetAsync(bucket_cnt, 0, NBUCK * CNT_PAD * sizeof(int), stream);

    setup_kernel<<<EDGE_BLOCKS + CONV_BLOCKS, 256, 0, stream>>>(
        (const float4*)X, Xb,
        (const int4*)rows, (const int4*)cols, (const float4*)vals,
        bucket_cnt, bucket_buf);

    ell_build_kernel<<<NBUCK, 512, 0, stream>>>(bucket_cnt, bucket_buf, ell, cnt);

    const int blocks = (N_NODES * TPR + 255) / 256;

    // layer 1: Xb -> e1
    spmm_fused_kernel<0><<<blocks, 256, 0, stream>>>(
        Xb, ego_a, cnt, (const int4*)ell, nullptr, nullptr, nullptr);
    // layer 2: e1 -> e2
    spmm_fused_kernel<0><<<blocks, 256, 0, stream>>>(
        ego_a, ego_b, cnt, (const int4*)ell, nullptr, nullptr, nullptr);
    // layer 3: e2 -> acc = (X + e1 + e2 + e3)/4, e3 in regs only
    spmm_fused_kernel<1><<<blocks, 256, 0, stream>>>(
        ego_b, nullptr, cnt, (const int4*)ell, Xb, ego_a, (float4*)acc);
}